// Round 1
// baseline (2083.743 us; speedup 1.0000x reference)
//
#include <hip/hip_runtime.h>
#include <math.h>

#define B_   128
#define L_   32
#define T_   31
#define V_   10000
#define IC_  2048
#define WD_  512
#define H_   512
#define D_   2560
#define G3_  1536  // 3*H

// ---- workspace layout (byte offsets, all 16B aligned where needed) ----
#define WS_ORDER 0           // int[128]
#define WS_LEN   512         // int[128]
#define WS_TOK   1024        // int[3968]  tok[t*128+b]
#define WS_H     16896       // float[128*512]
#define WS_GH    279040      // float[128*1536]
#define WS_GIIMG 1065472     // float[128*1536]
#define WS_GIW   1851904     // float[3968*1536]
#define WS_OUTS  26231296    // float[31*128*512]
// total: 34,357,760 bytes

// ---------------------------------------------------------------------------
// Prep: stable descending argsort of cap_lens (128 elems), emit order/lengths,
// captions_s (as float) to d_out tail, token table for embedding gather.
// ---------------------------------------------------------------------------
__global__ void k_prep(const int* __restrict__ captions,
                       const int* __restrict__ cap_lens,
                       int* __restrict__ order,
                       int* __restrict__ len_i,
                       int* __restrict__ tok,
                       float* __restrict__ out_tail) {
    __shared__ int s_len[B_];
    __shared__ int s_ord[B_];
    const int tid = threadIdx.x;
    if (tid < B_) s_len[tid] = cap_lens[tid];
    __syncthreads();
    if (tid < B_) {
        const int myl = s_len[tid];
        int rank = 0;
        for (int k = 0; k < B_; ++k) {
            const int lk = s_len[k];
            if (lk > myl || (lk == myl && k < tid)) rank++;
        }
        s_ord[rank] = tid;   // order[rank] = original index
    }
    __syncthreads();
    if (tid < B_) {
        const int o = s_ord[tid];
        order[tid] = o;
        const int ln = s_len[o] - 1;
        len_i[tid] = ln;
        out_tail[B_ * L_ + tid]      = (float)ln;  // lengths
        out_tail[B_ * L_ + B_ + tid] = (float)o;   // order
    }
    __syncthreads();
    for (int i = tid; i < B_ * L_; i += blockDim.x) {
        const int b = i / L_, l = i % L_;
        const int c = captions[s_ord[b] * L_ + l];
        out_tail[i] = (float)c;                    // captions_s
        if (l < T_) tok[l * B_ + b] = c;           // tok[t*B+b]
    }
}

// ---------------------------------------------------------------------------
// Generic NT GEMM: C[m][n] = sum_k A[row(m)][k] * B[n][k]  (+ bias[n])
// A row gather via gidx (nullable). Tiles: 64x64, BK=16, 256 thr, 4x4 micro.
// M must be a multiple of 64 and grid.y exact; N guarded; K multiple of 16.
// ---------------------------------------------------------------------------
__global__ __launch_bounds__(256) void gemm_nt(
    const float* __restrict__ A, int lda, const int* __restrict__ gidx,
    const float* __restrict__ Bm, int ldb,
    const float* __restrict__ bias,
    float* __restrict__ C, int ldc,
    int N, int K) {
    __shared__ float As[16][64];
    __shared__ float Bs[16][64];
    const int tid = threadIdx.x;
    const int m0 = blockIdx.y * 64;
    const int n0 = blockIdx.x * 64;

    const int li = tid >> 2;          // 0..63 (tile row for staging)
    const int lj = (tid & 3) << 2;    // 0,4,8,12 (k offset, float4)

    const int arow = gidx ? gidx[m0 + li] : (m0 + li);
    const float* aptr = A + (size_t)arow * lda + lj;
    const int brow = n0 + li;
    const bool bvalid = (brow < N);
    const float* bptr = Bm + (size_t)(bvalid ? brow : 0) * ldb + lj;

    const int tm = (tid & 15) << 2;
    const int tn = (tid >> 4) << 2;

    float acc[4][4] = {};

    for (int k0 = 0; k0 < K; k0 += 16) {
        const float4 av = *(const float4*)(aptr + k0);
        float4 bv = make_float4(0.f, 0.f, 0.f, 0.f);
        if (bvalid) bv = *(const float4*)(bptr + k0);
        __syncthreads();
        As[lj + 0][li] = av.x; As[lj + 1][li] = av.y;
        As[lj + 2][li] = av.z; As[lj + 3][li] = av.w;
        Bs[lj + 0][li] = bv.x; Bs[lj + 1][li] = bv.y;
        Bs[lj + 2][li] = bv.z; Bs[lj + 3][li] = bv.w;
        __syncthreads();
#pragma unroll
        for (int kk = 0; kk < 16; ++kk) {
            const float4 a = *(const float4*)&As[kk][tm];
            const float4 b = *(const float4*)&Bs[kk][tn];
            acc[0][0] = fmaf(a.x, b.x, acc[0][0]);
            acc[0][1] = fmaf(a.x, b.y, acc[0][1]);
            acc[0][2] = fmaf(a.x, b.z, acc[0][2]);
            acc[0][3] = fmaf(a.x, b.w, acc[0][3]);
            acc[1][0] = fmaf(a.y, b.x, acc[1][0]);
            acc[1][1] = fmaf(a.y, b.y, acc[1][1]);
            acc[1][2] = fmaf(a.y, b.z, acc[1][2]);
            acc[1][3] = fmaf(a.y, b.w, acc[1][3]);
            acc[2][0] = fmaf(a.z, b.x, acc[2][0]);
            acc[2][1] = fmaf(a.z, b.y, acc[2][1]);
            acc[2][2] = fmaf(a.z, b.z, acc[2][2]);
            acc[2][3] = fmaf(a.z, b.w, acc[2][3]);
            acc[3][0] = fmaf(a.w, b.x, acc[3][0]);
            acc[3][1] = fmaf(a.w, b.y, acc[3][1]);
            acc[3][2] = fmaf(a.w, b.z, acc[3][2]);
            acc[3][3] = fmaf(a.w, b.w, acc[3][3]);
        }
    }

#pragma unroll
    for (int r = 0; r < 4; ++r) {
        const int m = m0 + tm + r;
#pragma unroll
        for (int c = 0; c < 4; ++c) {
            const int n = n0 + tn + c;
            if (n < N) {
                float v = acc[r][c];
                if (bias) v += bias[n];
                C[(size_t)m * ldc + n] = v;
            }
        }
    }
}

// ---------------------------------------------------------------------------
// GRU gate elementwise: one thread per (b,c), c in [0,512).
// In-place h update + store to outs[t].
// ---------------------------------------------------------------------------
__global__ void k_gate(const float* __restrict__ gi_img,
                       const float* __restrict__ giw_t,
                       const float* __restrict__ gh,
                       float* __restrict__ h,
                       float* __restrict__ outs_t) {
    const int idx = blockIdx.x * blockDim.x + threadIdx.x;  // 0..65535
    const int b = idx >> 9;
    const int c = idx & 511;
    const size_t base = (size_t)b * G3_;
    const float ir = gi_img[base + c]        + giw_t[base + c];
    const float iz = gi_img[base + 512 + c]  + giw_t[base + 512 + c];
    const float in_ = gi_img[base + 1024 + c] + giw_t[base + 1024 + c];
    const float hr = gh[base + c];
    const float hz = gh[base + 512 + c];
    const float hn = gh[base + 1024 + c];
    const float r = 1.f / (1.f + expf(-(ir + hr)));
    const float z = 1.f / (1.f + expf(-(iz + hz)));
    const float n = tanhf(in_ + r * hn);
    const float hv = h[idx];
    const float hnew = (1.f - z) * n + z * hv;
    h[idx] = hnew;
    outs_t[idx] = hnew;
}

// ---------------------------------------------------------------------------
// Output projection: preds[b][t][v] = mask ? outs[t][b]·fc_w[v] + fc_b[v] : 0
// Rows m = t*128+b (64-row tile => fixed t). Lengths sorted descending so a
// tile is fully masked iff t >= len[b0]; then skip the K-loop, write zeros.
// ---------------------------------------------------------------------------
__global__ __launch_bounds__(256) void gemm_preds(
    const float* __restrict__ outs,   // (T*B, 512)
    const float* __restrict__ fcw,    // (V, 512)
    const float* __restrict__ fcb,    // (V,)
    const int* __restrict__ len_i,    // (B,)
    float* __restrict__ out) {        // (B, T, V)
    __shared__ float As[16][64];
    __shared__ float Bs[16][64];
    const int tid = threadIdx.x;
    const int m0 = blockIdx.y * 64;
    const int n0 = blockIdx.x * 64;
    const int t = m0 / B_;
    const int b0 = m0 % B_;

    const int tm = (tid & 15) << 2;
    const int tn = (tid >> 4) << 2;

    const bool skip = (t >= len_i[b0]);
    float acc[4][4] = {};

    if (!skip) {
        const int li = tid >> 2;
        const int lj = (tid & 3) << 2;
        const float* aptr = outs + (size_t)(m0 + li) * H_ + lj;
        const int brow = n0 + li;
        const bool bvalid = (brow < V_);
        const float* bptr = fcw + (size_t)(bvalid ? brow : 0) * H_ + lj;

        for (int k0 = 0; k0 < H_; k0 += 16) {
            const float4 av = *(const float4*)(aptr + k0);
            float4 bv = make_float4(0.f, 0.f, 0.f, 0.f);
            if (bvalid) bv = *(const float4*)(bptr + k0);
            __syncthreads();
            As[lj + 0][li] = av.x; As[lj + 1][li] = av.y;
            As[lj + 2][li] = av.z; As[lj + 3][li] = av.w;
            Bs[lj + 0][li] = bv.x; Bs[lj + 1][li] = bv.y;
            Bs[lj + 2][li] = bv.z; Bs[lj + 3][li] = bv.w;
            __syncthreads();
#pragma unroll
            for (int kk = 0; kk < 16; ++kk) {
                const float4 a = *(const float4*)&As[kk][tm];
                const float4 b = *(const float4*)&Bs[kk][tn];
                acc[0][0] = fmaf(a.x, b.x, acc[0][0]);
                acc[0][1] = fmaf(a.x, b.y, acc[0][1]);
                acc[0][2] = fmaf(a.x, b.z, acc[0][2]);
                acc[0][3] = fmaf(a.x, b.w, acc[0][3]);
                acc[1][0] = fmaf(a.y, b.x, acc[1][0]);
                acc[1][1] = fmaf(a.y, b.y, acc[1][1]);
                acc[1][2] = fmaf(a.y, b.z, acc[1][2]);
                acc[1][3] = fmaf(a.y, b.w, acc[1][3]);
                acc[2][0] = fmaf(a.z, b.x, acc[2][0]);
                acc[2][1] = fmaf(a.z, b.y, acc[2][1]);
                acc[2][2] = fmaf(a.z, b.z, acc[2][2]);
                acc[2][3] = fmaf(a.z, b.w, acc[2][3]);
                acc[3][0] = fmaf(a.w, b.x, acc[3][0]);
                acc[3][1] = fmaf(a.w, b.y, acc[3][1]);
                acc[3][2] = fmaf(a.w, b.z, acc[3][2]);
                acc[3][3] = fmaf(a.w, b.w, acc[3][3]);
            }
        }
    }

#pragma unroll
    for (int r = 0; r < 4; ++r) {
        const int b = b0 + tm + r;
        const bool act = !skip && (t < len_i[b]);
        const size_t base = (size_t)b * T_ * V_ + (size_t)t * V_;
#pragma unroll
        for (int c = 0; c < 4; ++c) {
            const int v = n0 + tn + c;
            if (v < V_) out[base + v] = act ? (acc[r][c] + fcb[v]) : 0.f;
        }
    }
}

// ---------------------------------------------------------------------------
extern "C" void kernel_launch(void* const* d_in, const int* in_sizes, int n_in,
                              void* d_out, int out_size, void* d_ws, size_t ws_size,
                              hipStream_t stream) {
    const float* image_code = (const float*)d_in[0];
    const int*   captions   = (const int*)d_in[1];
    const int*   cap_lens   = (const int*)d_in[2];
    const float* embed_w    = (const float*)d_in[3];
    const float* W_ih       = (const float*)d_in[4];
    const float* W_hh       = (const float*)d_in[5];
    const float* b_ih       = (const float*)d_in[6];
    const float* b_hh       = (const float*)d_in[7];
    const float* fc_w       = (const float*)d_in[8];
    const float* fc_b       = (const float*)d_in[9];
    const float* init_w     = (const float*)d_in[10];
    const float* init_b     = (const float*)d_in[11];

    float* out = (float*)d_out;
    char* ws = (char*)d_ws;
    int*   order  = (int*)(ws + WS_ORDER);
    int*   len_i  = (int*)(ws + WS_LEN);
    int*   tok    = (int*)(ws + WS_TOK);
    float* h      = (float*)(ws + WS_H);
    float* gh     = (float*)(ws + WS_GH);
    float* gi_img = (float*)(ws + WS_GIIMG);
    float* giw    = (float*)(ws + WS_GIW);
    float* outs   = (float*)(ws + WS_OUTS);

    // 1) sort + gathers + int-ish outputs
    hipLaunchKernelGGL(k_prep, dim3(1), dim3(128), 0, stream,
                       captions, cap_lens, order, len_i, tok,
                       out + (size_t)B_ * T_ * V_);

    // 2) h0 = ic_s @ init_w^T + init_b        (128x512, K=2048)
    hipLaunchKernelGGL(gemm_nt, dim3(H_ / 64, B_ / 64), dim3(256), 0, stream,
                       image_code, IC_, order, init_w, IC_, init_b, h, H_, H_, IC_);

    // 3) gi_img = ic_s @ W_ih[:, :2048]^T + b_ih   (128x1536, K=2048)
    hipLaunchKernelGGL(gemm_nt, dim3(G3_ / 64, B_ / 64), dim3(256), 0, stream,
                       image_code, IC_, order, W_ih, D_, b_ih, gi_img, G3_, G3_, IC_);

    // 4) giw = emb @ W_ih[:, 2048:]^T   (3968x1536, K=512), batched over all t
    hipLaunchKernelGGL(gemm_nt, dim3(G3_ / 64, (T_ * B_) / 64), dim3(256), 0, stream,
                       embed_w, WD_, tok, W_ih + IC_, D_, (const float*)nullptr,
                       giw, G3_, G3_, WD_);

    // 5) recurrence
    for (int t = 0; t < T_; ++t) {
        hipLaunchKernelGGL(gemm_nt, dim3(G3_ / 64, B_ / 64), dim3(256), 0, stream,
                           h, H_, (const int*)nullptr, W_hh, H_, b_hh, gh, G3_, G3_, H_);
        hipLaunchKernelGGL(k_gate, dim3((B_ * H_) / 256), dim3(256), 0, stream,
                           gi_img, giw + (size_t)t * B_ * G3_, gh, h,
                           outs + (size_t)t * B_ * H_);
    }

    // 6) output projection with mask + transpose store
    hipLaunchKernelGGL(gemm_preds, dim3((V_ + 63) / 64, (T_ * B_) / 64), dim3(256), 0, stream,
                       outs, fc_w, fc_b, len_i, out);
}

// Round 2
// 1328.582 us; speedup vs baseline: 1.5684x; 1.5684x over previous
//
#include <hip/hip_runtime.h>
#include <math.h>

#define B_   128
#define L_   32
#define T_   31
#define V_   10000
#define IC_  2048
#define WD_  512
#define H_   512
#define D_   2560
#define G3_  1536   // 3*H
#define NPAD_ 10112 // V padded to 79*128

typedef short short8 __attribute__((ext_vector_type(8)));
typedef float f32x4  __attribute__((ext_vector_type(4)));

__device__ __forceinline__ unsigned short f2bf(float f) {
    unsigned int u = __builtin_bit_cast(unsigned int, f);
    unsigned int r = (u + 0x7FFFu + ((u >> 16) & 1u)) >> 16;
    return (unsigned short)r;
}
__device__ __forceinline__ float bf2f(unsigned short h) {
    unsigned int u = ((unsigned int)h) << 16;
    return __builtin_bit_cast(float, u);
}
__device__ __forceinline__ f32x4 mfma16(short8 a, short8 b, f32x4 c) {
    return __builtin_amdgcn_mfma_f32_16x16x32_bf16(a, b, c, 0, 0, 0);
}

// ---- workspace layout (byte offsets) ----
#define WS_ORDER  0          // int[128]
#define WS_LEN    512        // int[128]
#define WS_TOK    1024       // int[3968]
#define WS_GIIMG  16896      // float[128*1536]   gi_img (+b_ih)
#define WS_GIFULL 803328     // bf16 [3968*1536]  gi = gi_img + emb@Wihw^T
#define WS_OUTS   12993024   // bf16 [32*128*512] row 0=h0, row (t+1)=h after step t
#define WS_FCW    17187328   // bf16 [10112*512]  fc_w padded, zero tail
// end: 27,542,016 bytes

// ---------------------------------------------------------------------------
__global__ void k_prep(const int* __restrict__ captions,
                       const int* __restrict__ cap_lens,
                       int* __restrict__ order,
                       int* __restrict__ len_i,
                       int* __restrict__ tok,
                       float* __restrict__ out_tail) {
    __shared__ int s_len[B_];
    __shared__ int s_ord[B_];
    const int tid = threadIdx.x;
    if (tid < B_) s_len[tid] = cap_lens[tid];
    __syncthreads();
    if (tid < B_) {
        const int myl = s_len[tid];
        int rank = 0;
        for (int k = 0; k < B_; ++k) {
            const int lk = s_len[k];
            if (lk > myl || (lk == myl && k < tid)) rank++;
        }
        s_ord[rank] = tid;
    }
    __syncthreads();
    if (tid < B_) {
        const int o = s_ord[tid];
        order[tid] = o;
        const int ln = s_len[o] - 1;
        len_i[tid] = ln;
        out_tail[B_ * L_ + tid]      = (float)ln;
        out_tail[B_ * L_ + B_ + tid] = (float)o;
    }
    __syncthreads();
    for (int i = tid; i < B_ * L_; i += blockDim.x) {
        const int b = i / L_, l = i % L_;
        const int c = captions[s_ord[b] * L_ + l];
        out_tail[i] = (float)c;
        if (l < T_) tok[l * B_ + b] = c;
    }
}

// fc_w (10000x512 f32) -> bf16 padded to 10112 rows (zero tail)
__global__ void k_cvt_fcw(const float* __restrict__ src, unsigned short* __restrict__ dst) {
    const int idx = blockIdx.x * 256 + threadIdx.x;     // one uint4 (8 bf16) each
    const int row = idx >> 6;
    const int ch  = idx & 63;
    union { unsigned short u[8]; uint4 v; } r;
    if (row < V_) {
        const float* p = src + (size_t)row * 512 + ch * 8;
        const float4 x = *(const float4*)p;
        const float4 y = *(const float4*)(p + 4);
        r.u[0]=f2bf(x.x); r.u[1]=f2bf(x.y); r.u[2]=f2bf(x.z); r.u[3]=f2bf(x.w);
        r.u[4]=f2bf(y.x); r.u[5]=f2bf(y.y); r.u[6]=f2bf(y.z); r.u[7]=f2bf(y.w);
    } else {
        r.v = make_uint4(0, 0, 0, 0);
    }
    *(uint4*)&dst[(size_t)row * 512 + ch * 8] = r.v;
}

// ---------------------------------------------------------------------------
// 16B staging load, optional f32->bf16 convert
template<bool F32>
__device__ __forceinline__ uint4 load_cvt(const void* src, size_t off) {
    if constexpr (!F32) {
        return *(const uint4*)((const unsigned short*)src + off);
    } else {
        const float* p = (const float*)src + off;
        const float4 x = *(const float4*)p;
        const float4 y = *(const float4*)(p + 4);
        union { unsigned short u[8]; uint4 v; } r;
        r.u[0]=f2bf(x.x); r.u[1]=f2bf(x.y); r.u[2]=f2bf(x.z); r.u[3]=f2bf(x.w);
        r.u[4]=f2bf(y.x); r.u[5]=f2bf(y.y); r.u[6]=f2bf(y.z); r.u[7]=f2bf(y.w);
        return r.v;
    }
}

// epilogues
struct EpiBiasF32 {               // gi_img
    float* C; int ldc; const float* bias;
    __device__ void operator()(int m, int n, float v) const {
        C[(size_t)m * ldc + n] = v + bias[n];
    }
};
struct EpiBiasBF16 {              // h0 -> outs_bf row block 0
    unsigned short* C; int ldc; const float* bias;
    __device__ void operator()(int m, int n, float v) const {
        C[(size_t)m * ldc + n] = f2bf(v + bias[n]);
    }
};
struct EpiAdd2D {                 // gi_full = giw + gi_img[b]
    unsigned short* C; int ldc; const float* add; int addld;
    __device__ void operator()(int m, int n, float v) const {
        C[(size_t)m * ldc + n] = f2bf(v + add[(size_t)(m & 127) * addld + n]);
    }
};
struct EpiPreds {                 // masked transpose store
    float* out; const float* fcb; const int* len;
    __device__ void operator()(int m, int n, float v) const {
        if (n >= V_) return;
        const int t = m >> 7, b = m & 127;
        const float r = (t < len[b]) ? (v + fcb[n]) : 0.f;
        out[(size_t)b * T_ * V_ + (size_t)t * V_ + n] = r;
    }
};

// ---------------------------------------------------------------------------
// NT GEMM, 128x128 tile, BK=32, 256 thr / 4 waves, bf16 MFMA 16x16x32.
// A rows optionally gathered via gidx. M,N multiples of 128 (pad upstream),
// K multiple of 32. C written via epilogue functor per element.
// ---------------------------------------------------------------------------
template<bool AF32, bool BF32, class Epi>
__global__ __launch_bounds__(256) void gemm128(
    const void* __restrict__ A, int lda, const int* __restrict__ gidx,
    const void* __restrict__ Bm, int ldb, int K, Epi epi)
{
    __shared__ unsigned short As[128 * 32];
    __shared__ unsigned short Bs[128 * 32];
    const int tid = threadIdx.x;
    const int m0 = blockIdx.y * 128, n0 = blockIdx.x * 128;
    const int w = tid >> 6, lane = tid & 63, quad = lane >> 4, lr = lane & 15;
    const int srow = tid >> 2, ch = tid & 3;
    const int wm = (w & 1) * 64, wn = (w >> 1) * 64;

    const int ar0 = gidx ? gidx[m0 + srow]      : (m0 + srow);
    const int ar1 = gidx ? gidx[m0 + srow + 64] : (m0 + srow + 64);
    const int br0 = n0 + srow, br1 = n0 + srow + 64;

    f32x4 acc[4][4];
    const f32x4 z4 = {0.f, 0.f, 0.f, 0.f};
#pragma unroll
    for (int i = 0; i < 4; ++i)
#pragma unroll
        for (int j = 0; j < 4; ++j) acc[i][j] = z4;

    for (int k0 = 0; k0 < K; k0 += 32) {
        const uint4 a0 = load_cvt<AF32>(A, (size_t)ar0 * lda + k0 + ch * 8);
        const uint4 a1 = load_cvt<AF32>(A, (size_t)ar1 * lda + k0 + ch * 8);
        const uint4 b0 = load_cvt<BF32>(Bm, (size_t)br0 * ldb + k0 + ch * 8);
        const uint4 b1 = load_cvt<BF32>(Bm, (size_t)br1 * ldb + k0 + ch * 8);
        __syncthreads();
        *(uint4*)&As[(srow)      * 32 + ch * 8] = a0;
        *(uint4*)&As[(srow + 64) * 32 + ch * 8] = a1;
        *(uint4*)&Bs[(srow)      * 32 + ch * 8] = b0;
        *(uint4*)&Bs[(srow + 64) * 32 + ch * 8] = b1;
        __syncthreads();
        short8 af[4], bfr[4];
#pragma unroll
        for (int i = 0; i < 4; ++i) af[i]  = *(const short8*)&As[(wm + i * 16 + lr) * 32 + quad * 8];
#pragma unroll
        for (int j = 0; j < 4; ++j) bfr[j] = *(const short8*)&Bs[(wn + j * 16 + lr) * 32 + quad * 8];
#pragma unroll
        for (int i = 0; i < 4; ++i)
#pragma unroll
            for (int j = 0; j < 4; ++j) acc[i][j] = mfma16(af[i], bfr[j], acc[i][j]);
    }

#pragma unroll
    for (int i = 0; i < 4; ++i)
#pragma unroll
        for (int r = 0; r < 4; ++r) {
            const int m = m0 + wm + i * 16 + quad * 4 + r;
#pragma unroll
            for (int j = 0; j < 4; ++j) {
                const int n = n0 + wn + j * 16 + lr;
                epi(m, n, acc[i][j][r]);
            }
        }
}

// ---------------------------------------------------------------------------
// One GRU step: gh = h @ W_hh^T (bf16 MFMA) fused with gate math.
// Grid (8,2): block (g, ih) computes gh rows [ih*64,+64) for the column
// triple {g*64+c, 512+g*64+c, 1024+g*64+c} (c in [0,64)), i.e. permuted
// W_hh rows [g*192, +192). Epilogue: gates + h update, h stored bf16.
// ---------------------------------------------------------------------------
__global__ __launch_bounds__(256) void k_step(
    const unsigned short* __restrict__ h_in,   // (128,512) bf16
    const float* __restrict__ whh,             // (1536,512) f32
    const unsigned short* __restrict__ gi_t,   // (128,1536) bf16 (incl b_ih)
    const float* __restrict__ b_hh,
    unsigned short* __restrict__ h_out)        // (128,512) bf16
{
    __shared__ unsigned short As[64 * 32];
    __shared__ unsigned short Bs[192 * 32];
    __shared__ float gh[64 * 193];
    const int tid = threadIdx.x;
    const int g = blockIdx.x;    // 0..7
    const int ih = blockIdx.y;   // 0..1
    const int w = tid >> 6, lane = tid & 63, quad = lane >> 4, lr = lane & 15;
    const int srow = tid >> 2, ch = tid & 3;

    f32x4 acc[4][3];
    const f32x4 z4 = {0.f, 0.f, 0.f, 0.f};
#pragma unroll
    for (int i = 0; i < 4; ++i)
#pragma unroll
        for (int j = 0; j < 3; ++j) acc[i][j] = z4;

    // permuted B row -> W_hh source row
    int bsrc[3];
#pragma unroll
    for (int l = 0; l < 3; ++l) {
        const int brow = l * 64 + srow;                  // 0..191
        bsrc[l] = (brow / 64) * 512 + g * 64 + (brow % 64);
    }
    const unsigned short* aptr = h_in + (size_t)(ih * 64 + srow) * 512 + ch * 8;

    for (int k0 = 0; k0 < 512; k0 += 32) {
        const uint4 a0 = *(const uint4*)(aptr + k0);
        uint4 bv[3];
#pragma unroll
        for (int l = 0; l < 3; ++l)
            bv[l] = load_cvt<true>(whh, (size_t)bsrc[l] * 512 + k0 + ch * 8);
        __syncthreads();
        *(uint4*)&As[srow * 32 + ch * 8] = a0;
#pragma unroll
        for (int l = 0; l < 3; ++l)
            *(uint4*)&Bs[(l * 64 + srow) * 32 + ch * 8] = bv[l];
        __syncthreads();
        short8 af[4], bfr[3];
#pragma unroll
        for (int i = 0; i < 4; ++i) af[i] = *(const short8*)&As[(i * 16 + lr) * 32 + quad * 8];
#pragma unroll
        for (int j = 0; j < 3; ++j) bfr[j] = *(const short8*)&Bs[((3 * w + j) * 16 + lr) * 32 + quad * 8];
#pragma unroll
        for (int i = 0; i < 4; ++i)
#pragma unroll
            for (int j = 0; j < 3; ++j) acc[i][j] = mfma16(af[i], bfr[j], acc[i][j]);
    }

    __syncthreads();
#pragma unroll
    for (int i = 0; i < 4; ++i)
#pragma unroll
        for (int r = 0; r < 4; ++r)
#pragma unroll
            for (int j = 0; j < 3; ++j)
                gh[(i * 16 + quad * 4 + r) * 193 + (3 * w + j) * 16 + lr] = acc[i][j][r];
    __syncthreads();

    // gates: thread -> row=tid/4 (local), 16 cols
    const int row = tid >> 2;
    const int c0 = (tid & 3) * 16;
    const int b = ih * 64 + row;
#pragma unroll
    for (int k = 0; k < 16; ++k) {
        const int c = c0 + k;
        const int cg = g * 64 + c;
        const float ir = bf2f(gi_t[(size_t)b * G3_ + cg]);
        const float iz = bf2f(gi_t[(size_t)b * G3_ + 512 + cg]);
        const float in_ = bf2f(gi_t[(size_t)b * G3_ + 1024 + cg]);
        const float hr = gh[row * 193 + c]        + b_hh[cg];
        const float hz = gh[row * 193 + 64 + c]   + b_hh[512 + cg];
        const float hn = gh[row * 193 + 128 + c]  + b_hh[1024 + cg];
        const float r = 1.f / (1.f + expf(-(ir + hr)));
        const float zg = 1.f / (1.f + expf(-(iz + hz)));
        const float n = tanhf(in_ + r * hn);
        const float hold = bf2f(h_in[(size_t)b * 512 + cg]);
        const float hnew = (1.f - zg) * n + zg * hold;
        h_out[(size_t)b * 512 + cg] = f2bf(hnew);
    }
}

// ---------------------------------------------------------------------------
extern "C" void kernel_launch(void* const* d_in, const int* in_sizes, int n_in,
                              void* d_out, int out_size, void* d_ws, size_t ws_size,
                              hipStream_t stream) {
    const float* image_code = (const float*)d_in[0];
    const int*   captions   = (const int*)d_in[1];
    const int*   cap_lens   = (const int*)d_in[2];
    const float* embed_w    = (const float*)d_in[3];
    const float* W_ih       = (const float*)d_in[4];
    const float* W_hh       = (const float*)d_in[5];
    const float* b_ih       = (const float*)d_in[6];
    const float* b_hh       = (const float*)d_in[7];
    const float* fc_w       = (const float*)d_in[8];
    const float* fc_b       = (const float*)d_in[9];
    const float* init_w     = (const float*)d_in[10];
    const float* init_b     = (const float*)d_in[11];

    float* out = (float*)d_out;
    char* ws = (char*)d_ws;
    int*            order   = (int*)(ws + WS_ORDER);
    int*            len_i   = (int*)(ws + WS_LEN);
    int*            tok     = (int*)(ws + WS_TOK);
    float*          gi_img  = (float*)(ws + WS_GIIMG);
    unsigned short* gi_full = (unsigned short*)(ws + WS_GIFULL);
    unsigned short* outs_bf = (unsigned short*)(ws + WS_OUTS);
    unsigned short* fcw_bf  = (unsigned short*)(ws + WS_FCW);

    // 1) sort + token table + int-ish outputs
    hipLaunchKernelGGL(k_prep, dim3(1), dim3(128), 0, stream,
                       captions, cap_lens, order, len_i, tok,
                       out + (size_t)B_ * T_ * V_);

    // 2) fc_w -> bf16 (padded)
    hipLaunchKernelGGL(k_cvt_fcw, dim3((NPAD_ * 64) / 256), dim3(256), 0, stream,
                       fc_w, fcw_bf);

    // 3) gi_img = ic_s @ W_ih[:, :2048]^T + b_ih    (128 x 1536, K=2048)
    hipLaunchKernelGGL((gemm128<true, true, EpiBiasF32>), dim3(12, 1), dim3(256), 0, stream,
                       image_code, IC_, order, W_ih, D_, IC_,
                       EpiBiasF32{gi_img, G3_, b_ih});

    // 4) h0 = ic_s @ init_w^T + init_b -> outs_bf rows [0,128)
    hipLaunchKernelGGL((gemm128<true, true, EpiBiasBF16>), dim3(4, 1), dim3(256), 0, stream,
                       image_code, IC_, order, init_w, IC_, IC_,
                       EpiBiasBF16{outs_bf, H_, init_b});

    // 5) gi_full = emb @ W_ih[:, 2048:]^T + gi_img[b]   (3968 x 1536, K=512)
    hipLaunchKernelGGL((gemm128<true, true, EpiAdd2D>), dim3(12, 31), dim3(256), 0, stream,
                       embed_w, WD_, tok, W_ih + IC_, D_, WD_,
                       EpiAdd2D{gi_full, G3_, gi_img, G3_});

    // 6) recurrence: 31 fused gemm+gate steps
    for (int t = 0; t < T_; ++t) {
        hipLaunchKernelGGL(k_step, dim3(8, 2), dim3(256), 0, stream,
                           outs_bf + (size_t)t * B_ * H_,
                           W_hh,
                           gi_full + (size_t)t * B_ * G3_,
                           b_hh,
                           outs_bf + (size_t)(t + 1) * B_ * H_);
    }

    // 7) preds = outs @ fc_w^T + fc_b, masked, transposed store
    hipLaunchKernelGGL((gemm128<false, false, EpiPreds>), dim3(NPAD_ / 128, 31), dim3(256), 0, stream,
                       outs_bf + (size_t)B_ * H_, H_, (const int*)nullptr,
                       fcw_bf, H_, H_,
                       EpiPreds{out, fc_b, len_i});
}

// Round 3
// 1076.036 us; speedup vs baseline: 1.9365x; 1.2347x over previous
//
#include <hip/hip_runtime.h>
#include <math.h>

#define B_   128
#define L_   32
#define T_   31
#define V_   10000
#define IC_  2048
#define WD_  512
#define H_   512
#define D_   2560
#define G3_  1536   // 3*H
#define NPAD_ 10112 // V padded to 79*128

typedef short short8 __attribute__((ext_vector_type(8)));
typedef float f32x4  __attribute__((ext_vector_type(4)));

__device__ __forceinline__ unsigned short f2bf(float f) {
    unsigned int u = __builtin_bit_cast(unsigned int, f);
    unsigned int r = (u + 0x7FFFu + ((u >> 16) & 1u)) >> 16;
    return (unsigned short)r;
}
__device__ __forceinline__ float bf2f(unsigned short h) {
    unsigned int u = ((unsigned int)h) << 16;
    return __builtin_bit_cast(float, u);
}
__device__ __forceinline__ f32x4 mfma16(short8 a, short8 b, f32x4 c) {
    return __builtin_amdgcn_mfma_f32_16x16x32_bf16(a, b, c, 0, 0, 0);
}

// ---- workspace layout (byte offsets) ----
#define WS_ORDER  0          // int[128]
#define WS_LEN    512        // int[128]
#define WS_TOK    1024       // int[3968] -> ends 16896
#define WS_BAR    16896      // int barrier counter (zeroed by k_prep)
#define WS_GIIMG  16960      // float[128*1536]          -> ends 803392
#define WS_WHH    803392     // bf16 [16][96][512] perm  -> ends 2376256
#define WS_GIFULL 2376256    // bf16 [3968*1536]         -> ends 14565952
#define WS_OUTS   14565952   // bf16 [32*128*512]        -> ends 18760256
#define WS_FCW    18760256   // bf16 [10112*512]         -> ends 29114944

// ---------------------------------------------------------------------------
__global__ void k_prep(const int* __restrict__ captions,
                       const int* __restrict__ cap_lens,
                       int* __restrict__ order,
                       int* __restrict__ len_i,
                       int* __restrict__ tok,
                       int* __restrict__ bar,
                       float* __restrict__ out_tail) {
    __shared__ int s_len[B_];
    __shared__ int s_ord[B_];
    const int tid = threadIdx.x;
    if (tid == 0) *bar = 0;
    if (tid < B_) s_len[tid] = cap_lens[tid];
    __syncthreads();
    if (tid < B_) {
        const int myl = s_len[tid];
        int rank = 0;
        for (int k = 0; k < B_; ++k) {
            const int lk = s_len[k];
            if (lk > myl || (lk == myl && k < tid)) rank++;
        }
        s_ord[rank] = tid;
    }
    __syncthreads();
    if (tid < B_) {
        const int o = s_ord[tid];
        order[tid] = o;
        const int ln = s_len[o] - 1;
        len_i[tid] = ln;
        out_tail[B_ * L_ + tid]      = (float)ln;
        out_tail[B_ * L_ + B_ + tid] = (float)o;
    }
    __syncthreads();
    for (int i = tid; i < B_ * L_; i += blockDim.x) {
        const int b = i / L_, l = i % L_;
        const int c = captions[s_ord[b] * L_ + l];
        out_tail[i] = (float)c;
        if (l < T_) tok[l * B_ + b] = c;
    }
}

// fc_w (10000x512 f32) -> bf16 padded to 10112 rows (zero tail)
__global__ void k_cvt_fcw(const float* __restrict__ src, unsigned short* __restrict__ dst) {
    const int idx = blockIdx.x * 256 + threadIdx.x;
    const int row = idx >> 6;
    const int ch  = idx & 63;
    union { unsigned short u[8]; uint4 v; } r;
    if (row < V_) {
        const float* p = src + (size_t)row * 512 + ch * 8;
        const float4 x = *(const float4*)p;
        const float4 y = *(const float4*)(p + 4);
        r.u[0]=f2bf(x.x); r.u[1]=f2bf(x.y); r.u[2]=f2bf(x.z); r.u[3]=f2bf(x.w);
        r.u[4]=f2bf(y.x); r.u[5]=f2bf(y.y); r.u[6]=f2bf(y.z); r.u[7]=f2bf(y.w);
    } else {
        r.v = make_uint4(0, 0, 0, 0);
    }
    *(uint4*)&dst[(size_t)row * 512 + ch * 8] = r.v;
}

// W_hh (1536x512 f32) -> bf16, permuted into 16 slices of 96x512:
// slice g, local row j (= gate*32 + c) <- source row gate*512 + g*32 + c
__global__ void k_cvt_whh(const float* __restrict__ whh, unsigned short* __restrict__ dst) {
    const int idx = blockIdx.x * 256 + threadIdx.x;   // one 8-elem group
    const size_t o = (size_t)idx * 8;
    const int g = (int)(o / (96 * 512));
    const int rem = (int)(o % (96 * 512));
    const int j = rem >> 9;
    const int k = rem & 511;
    const int srow = (j >> 5) * 512 + g * 32 + (j & 31);
    const float* p = whh + (size_t)srow * 512 + k;
    const float4 x = *(const float4*)p;
    const float4 y = *(const float4*)(p + 4);
    union { unsigned short u[8]; uint4 v; } r;
    r.u[0]=f2bf(x.x); r.u[1]=f2bf(x.y); r.u[2]=f2bf(x.z); r.u[3]=f2bf(x.w);
    r.u[4]=f2bf(y.x); r.u[5]=f2bf(y.y); r.u[6]=f2bf(y.z); r.u[7]=f2bf(y.w);
    *(uint4*)&dst[o] = r.v;
}

// ---------------------------------------------------------------------------
template<bool F32>
__device__ __forceinline__ uint4 load_cvt(const void* src, size_t off) {
    if constexpr (!F32) {
        return *(const uint4*)((const unsigned short*)src + off);
    } else {
        const float* p = (const float*)src + off;
        const float4 x = *(const float4*)p;
        const float4 y = *(const float4*)(p + 4);
        union { unsigned short u[8]; uint4 v; } r;
        r.u[0]=f2bf(x.x); r.u[1]=f2bf(x.y); r.u[2]=f2bf(x.z); r.u[3]=f2bf(x.w);
        r.u[4]=f2bf(y.x); r.u[5]=f2bf(y.y); r.u[6]=f2bf(y.z); r.u[7]=f2bf(y.w);
        return r.v;
    }
}

// epilogues
struct EpiBiasF32 {               // gi_img
    float* C; int ldc; const float* bias;
    __device__ void operator()(int m, int n, float v) const {
        C[(size_t)m * ldc + n] = v + bias[n];
    }
};
struct EpiBiasBF16 {              // h0 -> outs rows [0,128)
    unsigned short* C; int ldc; const float* bias;
    __device__ void operator()(int m, int n, float v) const {
        C[(size_t)m * ldc + n] = f2bf(v + bias[n]);
    }
};
struct EpiAdd2D {                 // gi_full = giw + gi_img[b] (+ b_hh for r,z)
    unsigned short* C; int ldc; const float* add; int addld; const float* bhh;
    __device__ void operator()(int m, int n, float v) const {
        const float extra = (n < 1024) ? bhh[n] : 0.f;
        C[(size_t)m * ldc + n] = f2bf(v + add[(size_t)(m & 127) * addld + n] + extra);
    }
};
struct EpiPreds {                 // masked transpose store
    float* out; const float* fcb; const int* len;
    __device__ void operator()(int m, int n, float v) const {
        if (n >= V_) return;
        const int t = m >> 7, b = m & 127;
        const float r = (t < len[b]) ? (v + fcb[n]) : 0.f;
        out[(size_t)b * T_ * V_ + (size_t)t * V_ + n] = r;
    }
};

// ---------------------------------------------------------------------------
// NT GEMM, 128x128 tile, BK=32, 256 thr / 4 waves, bf16 MFMA 16x16x32.
// ---------------------------------------------------------------------------
template<bool AF32, bool BF32, class Epi>
__global__ __launch_bounds__(256) void gemm128(
    const void* __restrict__ A, int lda, const int* __restrict__ gidx,
    const void* __restrict__ Bm, int ldb, int K, Epi epi)
{
    __shared__ unsigned short As[128 * 32];
    __shared__ unsigned short Bs[128 * 32];
    const int tid = threadIdx.x;
    const int m0 = blockIdx.y * 128, n0 = blockIdx.x * 128;
    const int w = tid >> 6, lane = tid & 63, quad = lane >> 4, lr = lane & 15;
    const int srow = tid >> 2, ch = tid & 3;
    const int wm = (w & 1) * 64, wn = (w >> 1) * 64;

    const int ar0 = gidx ? gidx[m0 + srow]      : (m0 + srow);
    const int ar1 = gidx ? gidx[m0 + srow + 64] : (m0 + srow + 64);
    const int br0 = n0 + srow, br1 = n0 + srow + 64;

    f32x4 acc[4][4];
    const f32x4 z4 = {0.f, 0.f, 0.f, 0.f};
#pragma unroll
    for (int i = 0; i < 4; ++i)
#pragma unroll
        for (int j = 0; j < 4; ++j) acc[i][j] = z4;

    for (int k0 = 0; k0 < K; k0 += 32) {
        const uint4 a0 = load_cvt<AF32>(A, (size_t)ar0 * lda + k0 + ch * 8);
        const uint4 a1 = load_cvt<AF32>(A, (size_t)ar1 * lda + k0 + ch * 8);
        const uint4 b0 = load_cvt<BF32>(Bm, (size_t)br0 * ldb + k0 + ch * 8);
        const uint4 b1 = load_cvt<BF32>(Bm, (size_t)br1 * ldb + k0 + ch * 8);
        __syncthreads();
        *(uint4*)&As[(srow)      * 32 + ch * 8] = a0;
        *(uint4*)&As[(srow + 64) * 32 + ch * 8] = a1;
        *(uint4*)&Bs[(srow)      * 32 + ch * 8] = b0;
        *(uint4*)&Bs[(srow + 64) * 32 + ch * 8] = b1;
        __syncthreads();
        short8 af[4], bfr[4];
#pragma unroll
        for (int i = 0; i < 4; ++i) af[i]  = *(const short8*)&As[(wm + i * 16 + lr) * 32 + quad * 8];
#pragma unroll
        for (int j = 0; j < 4; ++j) bfr[j] = *(const short8*)&Bs[(wn + j * 16 + lr) * 32 + quad * 8];
#pragma unroll
        for (int i = 0; i < 4; ++i)
#pragma unroll
            for (int j = 0; j < 4; ++j) acc[i][j] = mfma16(af[i], bfr[j], acc[i][j]);
    }

#pragma unroll
    for (int i = 0; i < 4; ++i)
#pragma unroll
        for (int r = 0; r < 4; ++r) {
            const int m = m0 + wm + i * 16 + quad * 4 + r;
#pragma unroll
            for (int j = 0; j < 4; ++j) {
                const int n = n0 + wn + j * 16 + lr;
                epi(m, n, acc[i][j][r]);
            }
        }
}

// ---------------------------------------------------------------------------
// Persistent recurrence: 32 blocks = (g 0..15) x (ih 0..1), 1 block/CU.
// Block (g,ih): gh cols {gate*512 + g*32 + c}, h rows [ih*64,+64).
// W slice (96x512) LDS-resident all 31 steps; grid barrier per step.
// ---------------------------------------------------------------------------
#define BS_STR 520
#define AS_STR 136
__global__ __launch_bounds__(256, 1) void k_recur(
    const unsigned short* __restrict__ whh_bf,   // (16,96,512)
    const unsigned short* __restrict__ gi_full,  // (31*128,1536)
    const float* __restrict__ b_hh,              // (1536)
    unsigned short* __restrict__ outs,           // (32,128,512)
    int* __restrict__ bar)
{
    __shared__ unsigned short Bs[96 * BS_STR];
    __shared__ unsigned short As[64 * AS_STR];
    const int tid = threadIdx.x;
    const int g = blockIdx.x & 15;
    const int ih = blockIdx.x >> 4;
    const int w = tid >> 6, lane = tid & 63, quad = lane >> 4, lr = lane & 15;

    // one-time: W slice -> LDS (pad stride 520 kills the 1024B bank stride)
    {
        const unsigned short* src = whh_bf + (size_t)g * 96 * 512;
        for (int i = tid; i < 96 * 32; i += 256) {
            const int row = i >> 5, c16 = i & 31;
            *(uint4*)&Bs[row * BS_STR + c16 * 8] = *(const uint4*)&src[row * 512 + c16 * 8];
        }
    }
    const int col0 = g * 32 + lr;
    const float bhn0 = b_hh[1024 + col0];
    const float bhn1 = b_hh[1024 + col0 + 16];
    __syncthreads();

    for (int step = 0; step < T_; ++step) {
        f32x4 acc[6];
#pragma unroll
        for (int j = 0; j < 6; ++j) acc[j] = (f32x4){0.f, 0.f, 0.f, 0.f};

        const unsigned short* hsrc = outs + (size_t)step * (128 * 512) + (size_t)ih * 64 * 512;
        for (int kc = 0; kc < 512; kc += 128) {
            __syncthreads();
            for (int i = tid; i < 64 * 16; i += 256) {
                const int row = i >> 4, c16 = i & 15;
                *(uint4*)&As[row * AS_STR + c16 * 8] =
                    *(const uint4*)&hsrc[(size_t)row * 512 + kc + c16 * 8];
            }
            __syncthreads();
#pragma unroll
            for (int kl = 0; kl < 128; kl += 32) {
                const short8 af = *(const short8*)&As[(w * 16 + lr) * AS_STR + kl + quad * 8];
#pragma unroll
                for (int j = 0; j < 6; ++j) {
                    const short8 bf = *(const short8*)&Bs[(j * 16 + lr) * BS_STR + kc + kl + quad * 8];
                    acc[j] = mfma16(af, bf, acc[j]);
                }
            }
        }

        // gates in registers: C-layout col=lane&15 (gh col), row=quad*4+r (batch)
        const size_t gbase = (size_t)step * 128 * 1536;
        unsigned short* hdst = outs + (size_t)(step + 1) * (128 * 512);
#pragma unroll
        for (int jj = 0; jj < 2; ++jj) {
            const int cg = g * 32 + jj * 16 + lr;
            const float bhn = jj ? bhn1 : bhn0;
#pragma unroll
            for (int r = 0; r < 4; ++r) {
                const int b = ih * 64 + w * 16 + quad * 4 + r;
                const size_t gb = gbase + (size_t)b * G3_;
                const float ir  = bf2f(gi_full[gb + cg]);
                const float iz  = bf2f(gi_full[gb + 512 + cg]);
                const float in_ = bf2f(gi_full[gb + 1024 + cg]);
                const float hr = acc[jj][r];
                const float hz = acc[2 + jj][r];
                const float hn = acc[4 + jj][r] + bhn;
                const float rg = 1.f / (1.f + __expf(-(ir + hr)));
                const float zg = 1.f / (1.f + __expf(-(iz + hz)));
                const float nn = tanhf(in_ + rg * hn);
                const float hold = bf2f(outs[(size_t)step * (128 * 512) + (size_t)b * 512 + cg]);
                const float hnew = (1.f - zg) * nn + zg * hold;
                hdst[(size_t)b * 512 + cg] = f2bf(hnew);
            }
        }

        // grid barrier (monotonic counter, device scope)
        __threadfence();
        __syncthreads();
        if (tid == 0) {
            __hip_atomic_fetch_add(bar, 1, __ATOMIC_RELEASE, __HIP_MEMORY_SCOPE_AGENT);
            const int target = 32 * (step + 1);
            while (__hip_atomic_load(bar, __ATOMIC_ACQUIRE, __HIP_MEMORY_SCOPE_AGENT) < target)
                __builtin_amdgcn_s_sleep(1);
        }
        __syncthreads();
        __threadfence();
    }
}

// ---------------------------------------------------------------------------
extern "C" void kernel_launch(void* const* d_in, const int* in_sizes, int n_in,
                              void* d_out, int out_size, void* d_ws, size_t ws_size,
                              hipStream_t stream) {
    const float* image_code = (const float*)d_in[0];
    const int*   captions   = (const int*)d_in[1];
    const int*   cap_lens   = (const int*)d_in[2];
    const float* embed_w    = (const float*)d_in[3];
    const float* W_ih       = (const float*)d_in[4];
    const float* W_hh       = (const float*)d_in[5];
    const float* b_ih       = (const float*)d_in[6];
    const float* b_hh       = (const float*)d_in[7];
    const float* fc_w       = (const float*)d_in[8];
    const float* fc_b       = (const float*)d_in[9];
    const float* init_w     = (const float*)d_in[10];
    const float* init_b     = (const float*)d_in[11];

    float* out = (float*)d_out;
    char* ws = (char*)d_ws;
    int*            order   = (int*)(ws + WS_ORDER);
    int*            len_i   = (int*)(ws + WS_LEN);
    int*            tok     = (int*)(ws + WS_TOK);
    int*            bar     = (int*)(ws + WS_BAR);
    float*          gi_img  = (float*)(ws + WS_GIIMG);
    unsigned short* whh_bf  = (unsigned short*)(ws + WS_WHH);
    unsigned short* gi_full = (unsigned short*)(ws + WS_GIFULL);
    unsigned short* outs_bf = (unsigned short*)(ws + WS_OUTS);
    unsigned short* fcw_bf  = (unsigned short*)(ws + WS_FCW);

    // 1) sort + token table + barrier reset + int-ish outputs
    hipLaunchKernelGGL(k_prep, dim3(1), dim3(128), 0, stream,
                       captions, cap_lens, order, len_i, tok, bar,
                       out + (size_t)B_ * T_ * V_);

    // 2) weight conversions
    hipLaunchKernelGGL(k_cvt_fcw, dim3((NPAD_ * 64) / 256), dim3(256), 0, stream,
                       fc_w, fcw_bf);
    hipLaunchKernelGGL(k_cvt_whh, dim3((G3_ * H_ / 8) / 256), dim3(256), 0, stream,
                       W_hh, whh_bf);

    // 3) gi_img = ic_s @ W_ih[:, :2048]^T + b_ih
    hipLaunchKernelGGL((gemm128<true, true, EpiBiasF32>), dim3(12, 1), dim3(256), 0, stream,
                       image_code, IC_, order, W_ih, D_, IC_,
                       EpiBiasF32{gi_img, G3_, b_ih});

    // 4) h0 = ic_s @ init_w^T + init_b -> outs rows [0,128)
    hipLaunchKernelGGL((gemm128<true, true, EpiBiasBF16>), dim3(4, 1), dim3(256), 0, stream,
                       image_code, IC_, order, init_w, IC_, IC_,
                       EpiBiasBF16{outs_bf, H_, init_b});

    // 5) gi_full = emb @ W_ih[:, 2048:]^T + gi_img[b] + b_hh(r,z)
    hipLaunchKernelGGL((gemm128<true, true, EpiAdd2D>), dim3(12, 31), dim3(256), 0, stream,
                       embed_w, WD_, tok, W_ih + IC_, D_, WD_,
                       EpiAdd2D{gi_full, G3_, gi_img, G3_, b_hh});

    // 6) persistent recurrence (31 steps, 1 launch, grid barrier per step)
    hipLaunchKernelGGL(k_recur, dim3(32), dim3(256), 0, stream,
                       whh_bf, gi_full, b_hh, outs_bf, bar);

    // 7) preds = outs @ fc_w^T + fc_b, masked, transposed store
    hipLaunchKernelGGL((gemm128<false, false, EpiPreds>), dim3(NPAD_ / 128, 31), dim3(256), 0, stream,
                       outs_bf + (size_t)B_ * H_, H_, (const int*)nullptr,
                       fcw_bf, H_, H_,
                       EpiPreds{out, fc_b, len_i});
}